// Round 4
// baseline (190.189 us; speedup 1.0000x reference)
//
#include <hip/hip_runtime.h>

typedef __bf16 bf16x8 __attribute__((ext_vector_type(8)));
typedef float f32x4 __attribute__((ext_vector_type(4)));
typedef float f32x16 __attribute__((ext_vector_type(16)));

#define MFMA16(a,b,c) __builtin_amdgcn_mfma_f32_16x16x32_bf16(a,b,c,0,0,0)
#define MFMA32(a,b,c) __builtin_amdgcn_mfma_f32_32x32x16_bf16(a,b,c,0,0,0)

static __device__ __forceinline__ unsigned short f2bf(float f){
  union{float f;unsigned u;}v; v.f=f;
  unsigned u=v.u;
  u += 0x7fffu + ((u>>16)&1u);
  return (unsigned short)(u>>16);
}
static __device__ __forceinline__ float bf2f(unsigned short h){
  union{unsigned u;float f;}v; v.u=((unsigned)h)<<16; return v.f;
}
static __device__ __forceinline__ unsigned cvtpk(float lo, float hi){
  unsigned r;
  asm("v_cvt_pk_bf16_f32 %0, %1, %2" : "=v"(r) : "v"(lo), "v"(hi));
  return r;
}
static __device__ __forceinline__ void gload16(const void* g, void* l){
  __builtin_amdgcn_global_load_lds(
    (const __attribute__((address_space(1))) unsigned int*)(uintptr_t)g,
    (__attribute__((address_space(3))) unsigned int*)(uintptr_t)l,
    16, 0, 0);
}

#define SCALE_QK 0.08838834764831845f
#define LOG2E    1.44269504088896340f
// logits are in log2 domain (scale*log2e folded into qp, log2e into biasc)
#define THR_L2   11.541560327111708f   /* 8 nat-units * log2e */

// XOR swizzles (short-index): byte ^= (row&7)<<4  (16B granule)
#define SWZ128(r,c) (((r)<<7) + ((c) ^ (((r)&7)<<3)))
#define SWZ64(r,c)  (((r)<<6) + ((c) ^ (((r)&7)<<3)))

// ---------------------------------------------------------------------------
// Kernel 1: q/k/v projections (bf16) + combined per-key bias.
//   t=0: qp = (query@q_w + q_b) * SCALE*LOG2E  [b][n][d]
//   t=1: kp = key@k_w                          [b][n][d]
//   t=2: vpt = (value@v_w + v_b)^T             [b][d][n]
//        biasc[b][n] = (value@vs_w + vs_b + att_bias) * LOG2E
// ---------------------------------------------------------------------------
__global__ __launch_bounds__(256) void k_proj(
    const float* __restrict__ query, const float* __restrict__ key,
    const float* __restrict__ value, const float* __restrict__ att_bias,
    const float* __restrict__ q_w, const float* __restrict__ q_b,
    const float* __restrict__ k_w, const float* __restrict__ v_w,
    const float* __restrict__ v_b, const float* __restrict__ vs_w,
    const float* __restrict__ vs_b,
    unsigned short* __restrict__ qp, unsigned short* __restrict__ kp,
    unsigned short* __restrict__ vpt, float* __restrict__ biasc)
{
  const int t = blockIdx.y;
  const float* X = (t==0) ? query : ((t==1) ? key : value);
  const float* W = (t==0) ? q_w  : ((t==1) ? k_w : v_w);
  const int tid = threadIdx.x;
  const int row0 = blockIdx.x * 64;

  __shared__ __align__(16) unsigned short Wt[128][136];
  __shared__ __align__(16) unsigned short Xs[64][136];
  __shared__ float vsw_s[128];

  #pragma unroll 4
  for (int i=0;i<16;i++){
    int idx = tid*64 + i*4;
    float4 v4 = *(const float4*)(W + idx);
    Wt[(idx+0)&127][(idx+0)>>7] = f2bf(v4.x);
    Wt[(idx+1)&127][(idx+1)>>7] = f2bf(v4.y);
    Wt[(idx+2)&127][(idx+2)>>7] = f2bf(v4.z);
    Wt[(idx+3)&127][(idx+3)>>7] = f2bf(v4.w);
  }
  {
    const float* Xb = X + (size_t)row0*128;
    #pragma unroll
    for (int i=0;i<8;i++){
      int f4 = i*256 + tid;
      int row = f4>>5, c4 = f4&31;
      float4 v = *(const float4*)(Xb + row*128 + c4*4);
      ushort4 h;
      h.x = f2bf(v.x); h.y = f2bf(v.y); h.z = f2bf(v.z); h.w = f2bf(v.w);
      *(ushort4*)&Xs[row][c4*4] = h;
    }
  }
  if (t==2 && tid<128) vsw_s[tid] = vs_w[tid];
  __syncthreads();

  const int w = tid>>6, lane = tid&63, lr = lane&15, lg = lane>>4;
  f32x4 acc[8];
  #pragma unroll
  for (int nt=0;nt<8;nt++) acc[nt] = (f32x4){0.f,0.f,0.f,0.f};
  #pragma unroll
  for (int kk=0;kk<4;kk++){
    bf16x8 a = *(const bf16x8*)&Xs[w*16+lr][kk*32+lg*8];
    #pragma unroll
    for (int nt=0;nt<8;nt++){
      bf16x8 bb = *(const bf16x8*)&Wt[nt*16+lr][kk*32+lg*8];
      acc[nt] = MFMA16(a,bb,acc[nt]);
    }
  }
  const float* bias = (t==0) ? q_b : ((t==2) ? v_b : (const float*)nullptr);
  const float sc = (t==0) ? (SCALE_QK*LOG2E) : 1.f;
  #pragma unroll
  for (int nt=0;nt<8;nt++){
    int col = nt*16+lr;
    float bv = bias ? bias[col] : 0.f;
    #pragma unroll
    for (int r=0;r<4;r++){
      int row = row0 + w*16 + lg*4 + r;
      unsigned short h = f2bf((acc[nt][r] + bv) * sc);
      if (t==0)      qp[(size_t)row*128+col] = h;
      else if (t==1) kp[(size_t)row*128+col] = h;
      else {
        int bi = row>>12, n = row&4095;
        vpt[((size_t)bi*128+col)*4096 + n] = h;
      }
    }
  }
  if (t==2){
    int rl = tid>>2, part = tid&3;
    float s = 0.f;
    #pragma unroll
    for (int j=0;j<32;j++){
      int d = part*32+j;
      s += bf2f(Xs[rl][d]) * vsw_s[d];
    }
    s += __shfl_xor(s,1);
    s += __shfl_xor(s,2);
    if ((tid&3)==0){
      int rg = row0 + rl;
      biasc[rg] = (s + vs_b[0] + att_bias[rg]) * LOG2E;
    }
  }
}

// ---------------------------------------------------------------------------
// Kernel 2: flash attention. Flat grid 1024, XCD-aware decode:
//   xcd = f&7 owns (b,split) groups {2*xcd, 2*xcd+1} -> per-XCD KV set = 1MB.
//   32x32x16 MFMA, swapped QK^T, in-lane softmax (exp2 domain), defer-max.
//   T14 staging: next tile global->reg issued BEFORE compute, ds_write after.
// ---------------------------------------------------------------------------
__global__ __launch_bounds__(256,3) void k_flash(
    const unsigned short* __restrict__ qp, const unsigned short* __restrict__ kp,
    const unsigned short* __restrict__ vpt, const float* __restrict__ biasc,
    unsigned short* __restrict__ opart, float* __restrict__ ml)
{
  // XCD-aware decode (bijective over 1024 blocks)
  const int f = blockIdx.x;
  const int xcd = f & 7, slot = f >> 3;
  const int group = xcd*2 + (slot>>6);
  const int b = group>>2, split = group&3;
  const int q0 = (slot & 63) * 64;

  const int tid = threadIdx.x;
  const int w = tid>>6, lane = tid&63;
  const int l31 = lane&31, hi = lane>>5;
  const int wr = w>>1, wc = w&1;

  __shared__ __align__(16) unsigned short Ks[64*128];   // [k][d] swizzled
  __shared__ __align__(16) unsigned short Vs[128*64];   // [d][k] swizzled
  __shared__ __align__(16) float Bs[1024];

  const unsigned short* kbase = kp  + (size_t)(b*4096 + split*1024)*128;
  const unsigned short* vbase = vpt + (size_t)b*128*4096 + split*1024;
  const float* bbase = biasc + b*4096 + split*1024;

  gload16(bbase + w*256 + lane*4, &Bs[w*256]);
  bf16x8 qf[8];
  {
    const unsigned short* qrow = qp + ((size_t)(b*4096 + q0 + wr*32 + l31))*128;
    #pragma unroll
    for (int kk=0;kk<8;kk++) qf[kk] = *(const bf16x8*)(qrow + kk*16 + hi*8);
  }

  // ---- staging helpers (per-thread 4 chunks of 16B for K, 4 for V)
  const char* kbB = (const char*)kbase;
  const char* vbB = (const char*)vbase;
  uint4 pf[8];

  #define LOAD_TILE(k0_) do{                                            \
    _Pragma("unroll")                                                   \
    for (int i=0;i<4;i++){                                              \
      int g = i*256 + tid;                                              \
      pf[i]   = *(const uint4*)(kbB + (size_t)(k0_)*256 + g*16);        \
      int d_  = g>>3, c16 = g&7;                                        \
      pf[4+i] = *(const uint4*)(vbB + (size_t)d_*8192 + (size_t)(k0_)*2 + c16*16); \
    }                                                                   \
  }while(0)

  #define WRITE_TILE() do{                                              \
    _Pragma("unroll")                                                   \
    for (int i=0;i<4;i++){                                              \
      int g = i*256 + tid;                                              \
      int kr = g>>4, kc = g&15;                                         \
      *(uint4*)((char*)Ks + kr*256 + ((kc*16) ^ ((kr&7)*16))) = pf[i];  \
      int d_ = g>>3, c16 = g&7;                                         \
      *(uint4*)((char*)Vs + d_*128 + ((c16*16) ^ ((d_&7)*16))) = pf[4+i]; \
    }                                                                   \
  }while(0)

  float m_run = -INFINITY, l_run = 0.f;
  f32x16 acc0 = {}, acc1 = {};

  // prologue: stage tile 0
  LOAD_TILE(0);
  WRITE_TILE();
  __syncthreads();   // drains bias gload + makes tile 0 visible

  for (int t=0;t<16;t++){
    // issue next tile's loads (latency hides under compute below)
    if (t<15) LOAD_TILE((t+1)*64);

    // ---- QK^T (swapped): lane holds 32 P-values for q = wr*32+l31
    f32x16 sc0 = {}, sc1 = {};
    __builtin_amdgcn_s_setprio(1);
    #pragma unroll
    for (int kk=0;kk<8;kk++){
      bf16x8 a0 = *(const bf16x8*)&Ks[SWZ128(l31,      kk*16 + hi*8)];
      bf16x8 a1 = *(const bf16x8*)&Ks[SWZ128(32 + l31, kk*16 + hi*8)];
      sc0 = MFMA32(a0, qf[kk], sc0);
      sc1 = MFMA32(a1, qf[kk], sc1);
    }
    __builtin_amdgcn_s_setprio(0);

    // ---- bias add + tile max (lane's k = c + 8*rg + 4*hi [+32 for sc1])
    const float* Bt = &Bs[t*64];
    float tmax = -1e30f;
    #pragma unroll
    for (int rg=0; rg<4; rg++){
      float4 b0 = *(const float4*)&Bt[rg*8 + hi*4];
      float4 b1 = *(const float4*)&Bt[32 + rg*8 + hi*4];
      #pragma unroll
      for (int c=0;c<4;c++){
        sc0[rg*4+c] += ((const float*)&b0)[c];
        sc1[rg*4+c] += ((const float*)&b1)[c];
        tmax = fmaxf(tmax, fmaxf(sc0[rg*4+c], sc1[rg*4+c]));
      }
    }
    tmax = fmaxf(tmax, __shfl_xor(tmax, 32));

    // ---- defer-max (log2 units; exact when skipped: corr==1)
    if (!__all(tmax <= m_run + THR_L2)){
      float mn = fmaxf(m_run, tmax);
      float corr = __builtin_exp2f(m_run - mn);
      m_run = mn;
      l_run *= corr;
      #pragma unroll
      for (int reg=0; reg<16; reg++){
        int qn = (reg&3) + 8*(reg>>2) + 4*hi;
        float ca = __shfl(corr, qn);
        acc0[reg] *= ca; acc1[reg] *= ca;
      }
    }

    // ---- exp2 + row sum
    float rs = 0.f;
    #pragma unroll
    for (int i=0;i<16;i++){
      sc0[i] = __builtin_exp2f(sc0[i]-m_run); rs += sc0[i];
      sc1[i] = __builtin_exp2f(sc1[i]-m_run); rs += sc1[i];
    }
    rs += __shfl_xor(rs, 32);
    l_run += rs;

    // ---- pack P to bf16
    unsigned pk0[8], pk1[8];
    #pragma unroll
    for (int rg=0; rg<4; rg++){
      pk0[rg*2+0] = cvtpk(sc0[rg*4+0], sc0[rg*4+1]);
      pk0[rg*2+1] = cvtpk(sc0[rg*4+2], sc0[rg*4+3]);
      pk1[rg*2+0] = cvtpk(sc1[rg*4+0], sc1[rg*4+1]);
      pk1[rg*2+1] = cvtpk(sc1[rg*4+2], sc1[rg*4+3]);
    }

    // ---- A-frag half-exchange + PV
    __builtin_amdgcn_s_setprio(1);
    #pragma unroll
    for (int kt=0; kt<4; kt++){
      const unsigned* pk = (kt<2)? pk0 : pk1;
      const int tA = 2*(kt&1);
      unsigned X0 = pk[tA*2+0], X1 = pk[tA*2+1];
      unsigned Y0 = pk[tA*2+2], Y1 = pk[tA*2+3];
      unsigned X0s = __shfl_xor(X0,32), X1s = __shfl_xor(X1,32);
      unsigned Y0s = __shfl_xor(Y0,32), Y1s = __shfl_xor(Y1,32);
      union { unsigned u[4]; bf16x8 v; } pu;
      pu.u[0] = hi ? Y0s : X0;
      pu.u[1] = hi ? Y1s : X1;
      pu.u[2] = hi ? Y0  : X0s;
      pu.u[3] = hi ? Y1  : X1s;
      bf16x8 v0 = *(const bf16x8*)&Vs[SWZ64(wc*64 +      l31, kt*16 + hi*8)];
      bf16x8 v1 = *(const bf16x8*)&Vs[SWZ64(wc*64 + 32 + l31, kt*16 + hi*8)];
      acc0 = MFMA32(pu.v, v0, acc0);
      acc1 = MFMA32(pu.v, v1, acc1);
    }
    __builtin_amdgcn_s_setprio(0);

    __syncthreads();           // all waves done reading tile t (drains pf loads)
    if (t<15){
      WRITE_TILE();            // swizzled ds_write of tile t+1
      __syncthreads();         // tile t+1 visible
    }
  }

  // ---- epilogue
  const size_t rowbase = (size_t)split*16384 + (size_t)b*4096 + q0;
  #pragma unroll
  for (int reg=0; reg<16; reg++){
    int qn = (reg&3) + 8*(reg>>2) + 4*hi;
    float lv = __shfl(l_run, qn);
    float inv = 1.f/lv;
    size_t row = rowbase + wr*32 + qn;
    opart[row*128 + wc*64 +      l31] = f2bf(acc0[reg]*inv);
    opart[row*128 + wc*64 + 32 + l31] = f2bf(acc1[reg]*inv);
  }
  if (hi==0){
    size_t rg = rowbase + wr*32 + l31;
    ml[rg*2]   = m_run;     // log2 domain
    ml[rg*2+1] = l_run;
  }
  #undef LOAD_TILE
  #undef WRITE_TILE
}

// ---------------------------------------------------------------------------
// Kernel 3: merge 4 KV-split partials + out-projection. (m in log2 domain)
// ---------------------------------------------------------------------------
__global__ __launch_bounds__(256) void k_outproj(
    const unsigned short* __restrict__ opart, const float* __restrict__ ml,
    const float* __restrict__ p_w, const float* __restrict__ p_b,
    float* __restrict__ out)
{
  const int tid = threadIdx.x;
  const int row0 = blockIdx.x*64;
  __shared__ __align__(16) unsigned short Wt[128][136];
  __shared__ __align__(16) unsigned short Xs[64][136];
  __shared__ float wmg[4][64];

  #pragma unroll 4
  for (int i=0;i<16;i++){
    int idx = tid*64 + i*4;
    float4 v4 = *(const float4*)(p_w + idx);
    Wt[(idx+0)&127][(idx+0)>>7] = f2bf(v4.x);
    Wt[(idx+1)&127][(idx+1)>>7] = f2bf(v4.y);
    Wt[(idx+2)&127][(idx+2)>>7] = f2bf(v4.z);
    Wt[(idx+3)&127][(idx+3)>>7] = f2bf(v4.w);
  }
  if (tid < 64){
    int row = row0 + tid;
    float m[4], l[4];
    #pragma unroll
    for (int i=0;i<4;i++){
      m[i] = ml[((size_t)i*16384 + row)*2];
      l[i] = ml[((size_t)i*16384 + row)*2 + 1];
    }
    float M = fmaxf(fmaxf(m[0],m[1]),fmaxf(m[2],m[3]));
    float wi[4], wsum = 0.f;
    #pragma unroll
    for (int i=0;i<4;i++){ wi[i] = __builtin_exp2f(m[i]-M)*l[i]; wsum += wi[i]; }
    float inv = 1.f/wsum;
    #pragma unroll
    for (int i=0;i<4;i++) wmg[i][tid] = wi[i]*inv;
  }
  __syncthreads();
  #pragma unroll
  for (int i=0;i<4;i++){
    int e = tid*32 + i*8;
    int row = e>>7, col = e&127;
    float a8[8];
    #pragma unroll
    for (int j=0;j<8;j++) a8[j] = 0.f;
    #pragma unroll
    for (int s=0;s<4;s++){
      uint4 v = *(const uint4*)(opart + ((size_t)s*16384 + row0 + row)*128 + col);
      float wv = wmg[s][row];
      const unsigned short* hp = (const unsigned short*)&v;
      #pragma unroll
      for (int j=0;j<8;j++) a8[j] += wv * bf2f(hp[j]);
    }
    unsigned short h8[8];
    #pragma unroll
    for (int j=0;j<8;j++) h8[j] = f2bf(a8[j]);
    *(uint4*)&Xs[row][col] = *(const uint4*)h8;
  }
  __syncthreads();

  const int w=tid>>6, lane=tid&63, lr=lane&15, lg=lane>>4;
  f32x4 acc[8];
  #pragma unroll
  for (int nt=0;nt<8;nt++) acc[nt] = (f32x4){0.f,0.f,0.f,0.f};
  #pragma unroll
  for (int kk=0;kk<4;kk++){
    bf16x8 a = *(const bf16x8*)&Xs[w*16+lr][kk*32+lg*8];
    #pragma unroll
    for (int nt=0;nt<8;nt++){
      bf16x8 bb = *(const bf16x8*)&Wt[nt*16+lr][kk*32+lg*8];
      acc[nt] = MFMA16(a,bb,acc[nt]);
    }
  }
  #pragma unroll
  for (int nt=0;nt<8;nt++){
    int col = nt*16+lr;
    float pb = p_b[col];
    #pragma unroll
    for (int r=0;r<4;r++){
      int row = row0 + w*16 + lg*4 + r;
      out[(size_t)row*128+col] = acc[nt][r] + pb;
    }
  }
}

extern "C" void kernel_launch(void* const* d_in, const int* in_sizes, int n_in,
                              void* d_out, int out_size, void* d_ws, size_t ws_size,
                              hipStream_t stream) {
  (void)in_sizes; (void)n_in; (void)out_size; (void)ws_size;
  const float* query    = (const float*)d_in[0];
  const float* key      = (const float*)d_in[1];
  const float* value    = (const float*)d_in[2];
  const float* att_bias = (const float*)d_in[3];
  const float* q_w = (const float*)d_in[4];
  const float* q_b = (const float*)d_in[5];
  const float* k_w = (const float*)d_in[6];
  const float* v_w = (const float*)d_in[7];
  const float* v_b = (const float*)d_in[8];
  const float* vs_w = (const float*)d_in[9];
  const float* vs_b = (const float*)d_in[10];
  const float* p_w = (const float*)d_in[11];
  const float* p_b = (const float*)d_in[12];

  char* ws = (char*)d_ws;
  unsigned short* qp    = (unsigned short*)(ws);             // 4 MB
  unsigned short* kp    = (unsigned short*)(ws + 4194304);   // 4 MB
  unsigned short* vpt   = (unsigned short*)(ws + 8388608);   // 4 MB  [b][d][n]
  float*          biasc = (float*)(ws + 12582912);           // 64 KB
  unsigned short* opart = (unsigned short*)(ws + 12648448);  // 16 MB
  float*          ml    = (float*)(ws + 29425664);           // 512 KB

  hipLaunchKernelGGL(k_proj, dim3(256,3), dim3(256), 0, stream,
    query,key,value,att_bias,q_w,q_b,k_w,v_w,v_b,vs_w,vs_b,qp,kp,vpt,biasc);
  hipLaunchKernelGGL(k_flash, dim3(1024), dim3(256), 0, stream,
    qp,kp,vpt,biasc,opart,ml);
  hipLaunchKernelGGL(k_outproj, dim3(256), dim3(256), 0, stream,
    opart,ml,p_w,p_b,(float*)d_out);
}

// Round 5
// 121.918 us; speedup vs baseline: 1.5600x; 1.5600x over previous
//
#include <hip/hip_runtime.h>

typedef __bf16 bf16x8 __attribute__((ext_vector_type(8)));
typedef float f32x4 __attribute__((ext_vector_type(4)));
typedef float f32x16 __attribute__((ext_vector_type(16)));

#define MFMA16(a,b,c) __builtin_amdgcn_mfma_f32_16x16x32_bf16(a,b,c,0,0,0)
#define MFMA32(a,b,c) __builtin_amdgcn_mfma_f32_32x32x16_bf16(a,b,c,0,0,0)

static __device__ __forceinline__ unsigned short f2bf(float f){
  union{float f;unsigned u;}v; v.f=f;
  unsigned u=v.u;
  u += 0x7fffu + ((u>>16)&1u);
  return (unsigned short)(u>>16);
}
static __device__ __forceinline__ float bf2f(unsigned short h){
  union{unsigned u;float f;}v; v.u=((unsigned)h)<<16; return v.f;
}
static __device__ __forceinline__ unsigned cvtpk(float lo, float hi){
  unsigned r;
  asm("v_cvt_pk_bf16_f32 %0, %1, %2" : "=v"(r) : "v"(lo), "v"(hi));
  return r;
}
static __device__ __forceinline__ void gload16(const void* g, void* l){
  __builtin_amdgcn_global_load_lds(
    (const __attribute__((address_space(1))) unsigned int*)(uintptr_t)g,
    (__attribute__((address_space(3))) unsigned int*)(uintptr_t)l,
    16, 0, 0);
}

#define SCALE_QK 0.08838834764831845f
#define LOG2E    1.44269504088896340f
#define THR_L2   11.541560327111708f   /* 8 nat-units * log2e */

// XOR swizzles (short-index): byte ^= (row&7)<<4  (16B granule)
#define SWZ128(r,c) (((r)<<7) + ((c) ^ (((r)&7)<<3)))
#define SWZ64(r,c)  (((r)<<6) + ((c) ^ (((r)&7)<<3)))

// ---------------------------------------------------------------------------
// Kernel 1: q/k/v projections (bf16) + combined per-key bias (log2 domain).
// ---------------------------------------------------------------------------
__global__ __launch_bounds__(256) void k_proj(
    const float* __restrict__ query, const float* __restrict__ key,
    const float* __restrict__ value, const float* __restrict__ att_bias,
    const float* __restrict__ q_w, const float* __restrict__ q_b,
    const float* __restrict__ k_w, const float* __restrict__ v_w,
    const float* __restrict__ v_b, const float* __restrict__ vs_w,
    const float* __restrict__ vs_b,
    unsigned short* __restrict__ qp, unsigned short* __restrict__ kp,
    unsigned short* __restrict__ vpt, float* __restrict__ biasc)
{
  const int t = blockIdx.y;
  const float* X = (t==0) ? query : ((t==1) ? key : value);
  const float* W = (t==0) ? q_w  : ((t==1) ? k_w : v_w);
  const int tid = threadIdx.x;
  const int row0 = blockIdx.x * 64;

  __shared__ __align__(16) unsigned short Wt[128][136];
  __shared__ __align__(16) unsigned short Xs[64][136];
  __shared__ float vsw_s[128];

  #pragma unroll 4
  for (int i=0;i<16;i++){
    int idx = tid*64 + i*4;
    float4 v4 = *(const float4*)(W + idx);
    Wt[(idx+0)&127][(idx+0)>>7] = f2bf(v4.x);
    Wt[(idx+1)&127][(idx+1)>>7] = f2bf(v4.y);
    Wt[(idx+2)&127][(idx+2)>>7] = f2bf(v4.z);
    Wt[(idx+3)&127][(idx+3)>>7] = f2bf(v4.w);
  }
  {
    const float* Xb = X + (size_t)row0*128;
    #pragma unroll
    for (int i=0;i<8;i++){
      int f4 = i*256 + tid;
      int row = f4>>5, c4 = f4&31;
      float4 v = *(const float4*)(Xb + row*128 + c4*4);
      ushort4 h;
      h.x = f2bf(v.x); h.y = f2bf(v.y); h.z = f2bf(v.z); h.w = f2bf(v.w);
      *(ushort4*)&Xs[row][c4*4] = h;
    }
  }
  if (t==2 && tid<128) vsw_s[tid] = vs_w[tid];
  __syncthreads();

  const int w = tid>>6, lane = tid&63, lr = lane&15, lg = lane>>4;
  f32x4 acc[8];
  #pragma unroll
  for (int nt=0;nt<8;nt++) acc[nt] = (f32x4){0.f,0.f,0.f,0.f};
  #pragma unroll
  for (int kk=0;kk<4;kk++){
    bf16x8 a = *(const bf16x8*)&Xs[w*16+lr][kk*32+lg*8];
    #pragma unroll
    for (int nt=0;nt<8;nt++){
      bf16x8 bb = *(const bf16x8*)&Wt[nt*16+lr][kk*32+lg*8];
      acc[nt] = MFMA16(a,bb,acc[nt]);
    }
  }
  const float* bias = (t==0) ? q_b : ((t==2) ? v_b : (const float*)nullptr);
  const float sc = (t==0) ? (SCALE_QK*LOG2E) : 1.f;
  #pragma unroll
  for (int nt=0;nt<8;nt++){
    int col = nt*16+lr;
    float bv = bias ? bias[col] : 0.f;
    #pragma unroll
    for (int r=0;r<4;r++){
      int row = row0 + w*16 + lg*4 + r;
      unsigned short h = f2bf((acc[nt][r] + bv) * sc);
      if (t==0)      qp[(size_t)row*128+col] = h;
      else if (t==1) kp[(size_t)row*128+col] = h;
      else {
        int bi = row>>12, n = row&4095;
        vpt[((size_t)bi*128+col)*4096 + n] = h;
      }
    }
  }
  if (t==2){
    int rl = tid>>2, part = tid&3;
    float s = 0.f;
    #pragma unroll
    for (int j=0;j<32;j++){
      int d = part*32+j;
      s += bf2f(Xs[rl][d]) * vsw_s[d];
    }
    s += __shfl_xor(s,1);
    s += __shfl_xor(s,2);
    if ((tid&3)==0){
      int rg = row0 + rl;
      biasc[rg] = (s + vs_b[0] + att_bias[rg]) * LOG2E;
    }
  }
}

// ---------------------------------------------------------------------------
// Kernel 2: flash attention. XCD-aware flat grid (FETCH 30MB proven r4).
//   32x32x16 swapped QK^T, in-lane exp2 softmax, defer-max.
//   Staging: global_load_lds (zero VGPR) + LDS DOUBLE-BUFFER, T3 2-phase:
//     issue STAGE(t+1 -> buf^1) BEFORE compute(t); one barrier per tile
//     (its vmcnt(0) drain lands after ~500cy of compute; KV is L2-warm).
//   LDS 68KB -> 2 blocks/CU; launch_bounds(256,2) -> no VGPR spill (r4 bug).
// ---------------------------------------------------------------------------
__global__ __launch_bounds__(256,2) void k_flash(
    const unsigned short* __restrict__ qp, const unsigned short* __restrict__ kp,
    const unsigned short* __restrict__ vpt, const float* __restrict__ biasc,
    unsigned short* __restrict__ opart, float* __restrict__ ml)
{
  // XCD-aware decode (bijective over 1024 blocks; xcd = blk&7)
  const int f = blockIdx.x;
  const int xcd = f & 7, slot = f >> 3;
  const int group = xcd*2 + (slot>>6);
  const int b = group>>2, split = group&3;
  const int q0 = (slot & 63) * 64;

  const int tid = threadIdx.x;
  const int w = tid>>6, lane = tid&63;
  const int l31 = lane&31, hi = lane>>5;
  const int wr = w>>1, wc = w&1;

  __shared__ __align__(16) unsigned short Ks[2][64*128];   // [k][d] swizzled
  __shared__ __align__(16) unsigned short Vs[2][128*64];   // [d][k] swizzled
  __shared__ __align__(16) float Bs[1024];

  const unsigned short* kbase = kp  + (size_t)(b*4096 + split*1024)*128;
  const unsigned short* vbase = vpt + (size_t)b*128*4096 + split*1024;
  const float* bbase = biasc + b*4096 + split*1024;

  gload16(bbase + w*256 + lane*4, &Bs[w*256]);
  bf16x8 qf[8];
  {
    const unsigned short* qrow = qp + ((size_t)(b*4096 + q0 + wr*32 + l31))*128;
    #pragma unroll
    for (int kk=0;kk<8;kk++) qf[kk] = *(const bf16x8*)(qrow + kk*16 + hi*8);
  }

  // stage tile k0_ into buffer bf_: 8 gload16/thread-slot, src pre-XOR'd
  #define STAGE(bf_, k0_) do{                                                 \
    const char* kb_ = (const char*)kbase + (size_t)(k0_)*256;                 \
    _Pragma("unroll")                                                         \
    for (int i=0;i<4;i++){                                                    \
      int row = (w*4+i)*4 + (lane>>4);                                        \
      int cb  = (lane&15)*16;                                                 \
      gload16(kb_ + row*256 + (cb ^ ((row&7)*16)),                            \
              (char*)Ks[bf_] + (w*4+i)*1024);                                 \
    }                                                                         \
    const char* vb_ = (const char*)vbase + (size_t)(k0_)*2;                   \
    _Pragma("unroll")                                                         \
    for (int i=0;i<4;i++){                                                    \
      int row = (w*4+i)*8 + (lane>>3);                                        \
      int cb  = (lane&7)*16;                                                  \
      gload16(vb_ + (size_t)row*8192 + (cb ^ ((row&7)*16)),                   \
              (char*)Vs[bf_] + (w*4+i)*1024);                                 \
    }                                                                         \
  }while(0)

  float m_run = -INFINITY, l_run = 0.f;
  f32x16 acc0 = {}, acc1 = {};

  STAGE(0, 0);
  __syncthreads();   // drains bias + tile0 loads

  for (int t=0;t<16;t++){
    const int cur = t & 1;
    if (t<15) STAGE(cur^1, (t+1)*64);   // issue early; drained at tile-end barrier

    // ---- QK^T (swapped): lane holds 32 P-values for q = wr*32+l31
    const unsigned short* Kc = Ks[cur];
    const unsigned short* Vc = Vs[cur];
    f32x16 sc0 = {}, sc1 = {};
    __builtin_amdgcn_s_setprio(1);
    #pragma unroll
    for (int kk=0;kk<8;kk++){
      bf16x8 a0 = *(const bf16x8*)&Kc[SWZ128(l31,      kk*16 + hi*8)];
      bf16x8 a1 = *(const bf16x8*)&Kc[SWZ128(32 + l31, kk*16 + hi*8)];
      sc0 = MFMA32(a0, qf[kk], sc0);
      sc1 = MFMA32(a1, qf[kk], sc1);
    }
    __builtin_amdgcn_s_setprio(0);

    // ---- bias add + tile max (lane's k = c + 8*rg + 4*hi [+32 for sc1])
    const float* Bt = &Bs[t*64];
    float tmax = -1e30f;
    #pragma unroll
    for (int rg=0; rg<4; rg++){
      float4 b0 = *(const float4*)&Bt[rg*8 + hi*4];
      float4 b1 = *(const float4*)&Bt[32 + rg*8 + hi*4];
      #pragma unroll
      for (int c=0;c<4;c++){
        sc0[rg*4+c] += ((const float*)&b0)[c];
        sc1[rg*4+c] += ((const float*)&b1)[c];
        tmax = fmaxf(tmax, fmaxf(sc0[rg*4+c], sc1[rg*4+c]));
      }
    }
    tmax = fmaxf(tmax, __shfl_xor(tmax, 32));

    // ---- defer-max (log2 units; exact when skipped: corr==1)
    if (!__all(tmax <= m_run + THR_L2)){
      float mn = fmaxf(m_run, tmax);
      float corr = __builtin_exp2f(m_run - mn);
      m_run = mn;
      l_run *= corr;
      #pragma unroll
      for (int reg=0; reg<16; reg++){
        int qn = (reg&3) + 8*(reg>>2) + 4*hi;
        float ca = __shfl(corr, qn);
        acc0[reg] *= ca; acc1[reg] *= ca;
      }
    }

    // ---- exp2 + row sum
    float rs = 0.f;
    #pragma unroll
    for (int i=0;i<16;i++){
      sc0[i] = __builtin_exp2f(sc0[i]-m_run); rs += sc0[i];
      sc1[i] = __builtin_exp2f(sc1[i]-m_run); rs += sc1[i];
    }
    rs += __shfl_xor(rs, 32);
    l_run += rs;

    // ---- pack P to bf16
    unsigned pk0[8], pk1[8];
    #pragma unroll
    for (int rg=0; rg<4; rg++){
      pk0[rg*2+0] = cvtpk(sc0[rg*4+0], sc0[rg*4+1]);
      pk0[rg*2+1] = cvtpk(sc0[rg*4+2], sc0[rg*4+3]);
      pk1[rg*2+0] = cvtpk(sc1[rg*4+0], sc1[rg*4+1]);
      pk1[rg*2+1] = cvtpk(sc1[rg*4+2], sc1[rg*4+3]);
    }

    // ---- A-frag half-exchange + PV
    __builtin_amdgcn_s_setprio(1);
    #pragma unroll
    for (int kt=0; kt<4; kt++){
      const unsigned* pk = (kt<2)? pk0 : pk1;
      const int tA = 2*(kt&1);
      unsigned X0 = pk[tA*2+0], X1 = pk[tA*2+1];
      unsigned Y0 = pk[tA*2+2], Y1 = pk[tA*2+3];
      unsigned X0s = __shfl_xor(X0,32), X1s = __shfl_xor(X1,32);
      unsigned Y0s = __shfl_xor(Y0,32), Y1s = __shfl_xor(Y1,32);
      union { unsigned u[4]; bf16x8 v; } pu;
      pu.u[0] = hi ? Y0s : X0;
      pu.u[1] = hi ? Y1s : X1;
      pu.u[2] = hi ? Y0  : X0s;
      pu.u[3] = hi ? Y1  : X1s;
      bf16x8 v0 = *(const bf16x8*)&Vc[SWZ64(wc*64 +      l31, kt*16 + hi*8)];
      bf16x8 v1 = *(const bf16x8*)&Vc[SWZ64(wc*64 + 32 + l31, kt*16 + hi*8)];
      acc0 = MFMA32(pu.v, v0, acc0);
      acc1 = MFMA32(pu.v, v1, acc1);
    }
    __builtin_amdgcn_s_setprio(0);

    // one barrier/tile: drains STAGE(t+1) vmcnt (issued ~500cy ago, L2-warm)
    // and closes all waves' reads of buf cur before it's overwritten at t+2.
    __syncthreads();
  }
  #undef STAGE

  // ---- epilogue
  const size_t rowbase = (size_t)split*16384 + (size_t)b*4096 + q0;
  #pragma unroll
  for (int reg=0; reg<16; reg++){
    int qn = (reg&3) + 8*(reg>>2) + 4*hi;
    float lv = __shfl(l_run, qn);
    float inv = 1.f/lv;
    size_t row = rowbase + wr*32 + qn;
    opart[row*128 + wc*64 +      l31] = f2bf(acc0[reg]*inv);
    opart[row*128 + wc*64 + 32 + l31] = f2bf(acc1[reg]*inv);
  }
  if (hi==0){
    size_t rg = rowbase + wr*32 + l31;
    ml[rg*2]   = m_run;     // log2 domain
    ml[rg*2+1] = l_run;
  }
}

// ---------------------------------------------------------------------------
// Kernel 3: merge 4 KV-split partials + out-projection. (m in log2 domain)
// ---------------------------------------------------------------------------
__global__ __launch_bounds__(256) void k_outproj(
    const unsigned short* __restrict__ opart, const float* __restrict__ ml,
    const float* __restrict__ p_w, const float* __restrict__ p_b,
    float* __restrict__ out)
{
  const int tid = threadIdx.x;
  const int row0 = blockIdx.x*64;
  __shared__ __align__(16) unsigned short Wt[128][136];
  __shared__ __align__(16) unsigned short Xs[64][136];
  __shared__ float wmg[4][64];

  #pragma unroll 4
  for (int i=0;i<16;i++){
    int idx = tid*64 + i*4;
    float4 v4 = *(const float4*)(p_w + idx);
    Wt[(idx+0)&127][(idx+0)>>7] = f2bf(v4.x);
    Wt[(idx+1)&127][(idx+1)>>7] = f2bf(v4.y);
    Wt[(idx+2)&127][(idx+2)>>7] = f2bf(v4.z);
    Wt[(idx+3)&127][(idx+3)>>7] = f2bf(v4.w);
  }
  if (tid < 64){
    int row = row0 + tid;
    float m[4], l[4];
    #pragma unroll
    for (int i=0;i<4;i++){
      m[i] = ml[((size_t)i*16384 + row)*2];
      l[i] = ml[((size_t)i*16384 + row)*2 + 1];
    }
    float M = fmaxf(fmaxf(m[0],m[1]),fmaxf(m[2],m[3]));
    float wi[4], wsum = 0.f;
    #pragma unroll
    for (int i=0;i<4;i++){ wi[i] = __builtin_exp2f(m[i]-M)*l[i]; wsum += wi[i]; }
    float inv = 1.f/wsum;
    #pragma unroll
    for (int i=0;i<4;i++) wmg[i][tid] = wi[i]*inv;
  }
  __syncthreads();
  #pragma unroll
  for (int i=0;i<4;i++){
    int e = tid*32 + i*8;
    int row = e>>7, col = e&127;
    float a8[8];
    #pragma unroll
    for (int j=0;j<8;j++) a8[j] = 0.f;
    #pragma unroll
    for (int s=0;s<4;s++){
      uint4 v = *(const uint4*)(opart + ((size_t)s*16384 + row0 + row)*128 + col);
      float wv = wmg[s][row];
      const unsigned short* hp = (const unsigned short*)&v;
      #pragma unroll
      for (int j=0;j<8;j++) a8[j] += wv * bf2f(hp[j]);
    }
    unsigned short h8[8];
    #pragma unroll
    for (int j=0;j<8;j++) h8[j] = f2bf(a8[j]);
    *(uint4*)&Xs[row][col] = *(const uint4*)h8;
  }
  __syncthreads();

  const int w=tid>>6, lane=tid&63, lr=lane&15, lg=lane>>4;
  f32x4 acc[8];
  #pragma unroll
  for (int nt=0;nt<8;nt++) acc[nt] = (f32x4){0.f,0.f,0.f,0.f};
  #pragma unroll
  for (int kk=0;kk<4;kk++){
    bf16x8 a = *(const bf16x8*)&Xs[w*16+lr][kk*32+lg*8];
    #pragma unroll
    for (int nt=0;nt<8;nt++){
      bf16x8 bb = *(const bf16x8*)&Wt[nt*16+lr][kk*32+lg*8];
      acc[nt] = MFMA16(a,bb,acc[nt]);
    }
  }
  #pragma unroll
  for (int nt=0;nt<8;nt++){
    int col = nt*16+lr;
    float pb = p_b[col];
    #pragma unroll
    for (int r=0;r<4;r++){
      int row = row0 + w*16 + lg*4 + r;
      out[(size_t)row*128+col] = acc[nt][r] + pb;
    }
  }
}

extern "C" void kernel_launch(void* const* d_in, const int* in_sizes, int n_in,
                              void* d_out, int out_size, void* d_ws, size_t ws_size,
                              hipStream_t stream) {
  (void)in_sizes; (void)n_in; (void)out_size; (void)ws_size;
  const float* query    = (const float*)d_in[0];
  const float* key      = (const float*)d_in[1];
  const float* value    = (const float*)d_in[2];
  const float* att_bias = (const float*)d_in[3];
  const float* q_w = (const float*)d_in[4];
  const float* q_b = (const float*)d_in[5];
  const float* k_w = (const float*)d_in[6];
  const float* v_w = (const float*)d_in[7];
  const float* v_b = (const float*)d_in[8];
  const float* vs_w = (const float*)d_in[9];
  const float* vs_b = (const float*)d_in[10];
  const float* p_w = (const float*)d_in[11];
  const float* p_b = (const float*)d_in[12];

  char* ws = (char*)d_ws;
  unsigned short* qp    = (unsigned short*)(ws);             // 4 MB
  unsigned short* kp    = (unsigned short*)(ws + 4194304);   // 4 MB
  unsigned short* vpt   = (unsigned short*)(ws + 8388608);   // 4 MB  [b][d][n]
  float*          biasc = (float*)(ws + 12582912);           // 64 KB
  unsigned short* opart = (unsigned short*)(ws + 12648448);  // 16 MB
  float*          ml    = (float*)(ws + 29425664);           // 512 KB

  hipLaunchKernelGGL(k_proj, dim3(256,3), dim3(256), 0, stream,
    query,key,value,att_bias,q_w,q_b,k_w,v_w,v_b,vs_w,vs_b,qp,kp,vpt,biasc);
  hipLaunchKernelGGL(k_flash, dim3(1024), dim3(256), 0, stream,
    qp,kp,vpt,biasc,opart,ml);
  hipLaunchKernelGGL(k_outproj, dim3(256), dim3(256), 0, stream,
    opart,ml,p_w,p_b,(float*)d_out);
}

// Round 6
// 113.677 us; speedup vs baseline: 1.6731x; 1.0725x over previous
//
#include <hip/hip_runtime.h>

typedef __bf16 bf16x8 __attribute__((ext_vector_type(8)));
typedef float f32x4 __attribute__((ext_vector_type(4)));
typedef float f32x16 __attribute__((ext_vector_type(16)));

#define MFMA16(a,b,c) __builtin_amdgcn_mfma_f32_16x16x32_bf16(a,b,c,0,0,0)
#define MFMA32(a,b,c) __builtin_amdgcn_mfma_f32_32x32x16_bf16(a,b,c,0,0,0)

static __device__ __forceinline__ unsigned short f2bf(float f){
  union{float f;unsigned u;}v; v.f=f;
  unsigned u=v.u;
  u += 0x7fffu + ((u>>16)&1u);
  return (unsigned short)(u>>16);
}
static __device__ __forceinline__ float bf2f(unsigned short h){
  union{unsigned u;float f;}v; v.u=((unsigned)h)<<16; return v.f;
}
static __device__ __forceinline__ unsigned cvtpk(float lo, float hi){
  unsigned r;
  asm("v_cvt_pk_bf16_f32 %0, %1, %2" : "=v"(r) : "v"(lo), "v"(hi));
  return r;
}
static __device__ __forceinline__ void gload16(const void* g, void* l){
  __builtin_amdgcn_global_load_lds(
    (const __attribute__((address_space(1))) unsigned int*)(uintptr_t)g,
    (__attribute__((address_space(3))) unsigned int*)(uintptr_t)l,
    16, 0, 0);
}

#define SCALE_QK 0.08838834764831845f
#define LOG2E    1.44269504088896340f
#define THR_L2   11.541560327111708f   /* 8 nat-units * log2e */

// XOR swizzle (short-index), 128-col (256B-stride) tiles: byte ^= (row&7)<<4
#define SWZ128(r,c) (((r)<<7) + ((c) ^ (((r)&7)<<3)))

// ---------------------------------------------------------------------------
// Kernel 1: q/k/v projections (bf16) + combined per-key bias (log2 domain).
// ---------------------------------------------------------------------------
__global__ __launch_bounds__(256) void k_proj(
    const float* __restrict__ query, const float* __restrict__ key,
    const float* __restrict__ value, const float* __restrict__ att_bias,
    const float* __restrict__ q_w, const float* __restrict__ q_b,
    const float* __restrict__ k_w, const float* __restrict__ v_w,
    const float* __restrict__ v_b, const float* __restrict__ vs_w,
    const float* __restrict__ vs_b,
    unsigned short* __restrict__ qp, unsigned short* __restrict__ kp,
    unsigned short* __restrict__ vpt, float* __restrict__ biasc)
{
  const int t = blockIdx.y;
  const float* X = (t==0) ? query : ((t==1) ? key : value);
  const float* W = (t==0) ? q_w  : ((t==1) ? k_w : v_w);
  const int tid = threadIdx.x;
  const int row0 = blockIdx.x * 64;

  __shared__ __align__(16) unsigned short Wt[128][136];
  __shared__ __align__(16) unsigned short Xs[64][136];
  __shared__ float vsw_s[128];

  #pragma unroll 4
  for (int i=0;i<16;i++){
    int idx = tid*64 + i*4;
    float4 v4 = *(const float4*)(W + idx);
    Wt[(idx+0)&127][(idx+0)>>7] = f2bf(v4.x);
    Wt[(idx+1)&127][(idx+1)>>7] = f2bf(v4.y);
    Wt[(idx+2)&127][(idx+2)>>7] = f2bf(v4.z);
    Wt[(idx+3)&127][(idx+3)>>7] = f2bf(v4.w);
  }
  {
    const float* Xb = X + (size_t)row0*128;
    #pragma unroll
    for (int i=0;i<8;i++){
      int f4 = i*256 + tid;
      int row = f4>>5, c4 = f4&31;
      float4 v = *(const float4*)(Xb + row*128 + c4*4);
      ushort4 h;
      h.x = f2bf(v.x); h.y = f2bf(v.y); h.z = f2bf(v.z); h.w = f2bf(v.w);
      *(ushort4*)&Xs[row][c4*4] = h;
    }
  }
  if (t==2 && tid<128) vsw_s[tid] = vs_w[tid];
  __syncthreads();

  const int w = tid>>6, lane = tid&63, lr = lane&15, lg = lane>>4;
  f32x4 acc[8];
  #pragma unroll
  for (int nt=0;nt<8;nt++) acc[nt] = (f32x4){0.f,0.f,0.f,0.f};
  #pragma unroll
  for (int kk=0;kk<4;kk++){
    bf16x8 a = *(const bf16x8*)&Xs[w*16+lr][kk*32+lg*8];
    #pragma unroll
    for (int nt=0;nt<8;nt++){
      bf16x8 bb = *(const bf16x8*)&Wt[nt*16+lr][kk*32+lg*8];
      acc[nt] = MFMA16(a,bb,acc[nt]);
    }
  }
  const float* bias = (t==0) ? q_b : ((t==2) ? v_b : (const float*)nullptr);
  const float sc = (t==0) ? (SCALE_QK*LOG2E) : 1.f;
  #pragma unroll
  for (int nt=0;nt<8;nt++){
    int col = nt*16+lr;
    float bv = bias ? bias[col] : 0.f;
    #pragma unroll
    for (int r=0;r<4;r++){
      int row = row0 + w*16 + lg*4 + r;
      unsigned short h = f2bf((acc[nt][r] + bv) * sc);
      if (t==0)      qp[(size_t)row*128+col] = h;
      else if (t==1) kp[(size_t)row*128+col] = h;
      else {
        int bi = row>>12, n = row&4095;
        vpt[((size_t)bi*128+col)*4096 + n] = h;
      }
    }
  }
  if (t==2){
    int rl = tid>>2, part = tid&3;
    float s = 0.f;
    #pragma unroll
    for (int j=0;j<32;j++){
      int d = part*32+j;
      s += bf2f(Xs[rl][d]) * vsw_s[d];
    }
    s += __shfl_xor(s,1);
    s += __shfl_xor(s,2);
    if ((tid&3)==0){
      int rg = row0 + rl;
      biasc[rg] = (s + vs_b[0] + att_bias[rg]) * LOG2E;
    }
  }
}

// ---------------------------------------------------------------------------
// Kernel 2: flash attention. KVBLK=32, full LDS double-buffer, 4 blocks/CU.
//   XCD-aware flat grid (FETCH 8MB proven r5). 32x32x16 swapped QK^T,
//   in-lane exp2 softmax, defer-max. One barrier/tile, STAGE-before-compute.
//   V stored in row-pair layout: d-rows (64B) packed two-per-128B-LDS-row,
//   XOR-swizzled like K -> same proven read spread; staging source = exact
//   layout inverse (gload_lds linear dest).
//   LDS = 2*8K(K) + 2*8K(V) + 4K(bias) = 36KB.
// ---------------------------------------------------------------------------
__global__ __launch_bounds__(256,4) void k_flash(
    const unsigned short* __restrict__ qp, const unsigned short* __restrict__ kp,
    const unsigned short* __restrict__ vpt, const float* __restrict__ biasc,
    unsigned short* __restrict__ opart, float* __restrict__ ml)
{
  // XCD-aware decode (bijective over 1024 blocks; xcd = blk&7)
  const int f = blockIdx.x;
  const int xcd = f & 7, slot = f >> 3;
  const int group = xcd*2 + (slot>>6);
  const int b = group>>2, split = group&3;
  const int q0 = (slot & 63) * 64;

  const int tid = threadIdx.x;
  const int w = tid>>6, lane = tid&63;
  const int l31 = lane&31, hi = lane>>5;
  const int wr = w>>1, wc = w&1;

  __shared__ __align__(16) unsigned short Ks[2][32*128];  // [k][d] swizzled
  __shared__ __align__(16) unsigned short Vs[2][64*64];   // row-pair layout
  __shared__ __align__(16) float Bs[1024];

  const unsigned short* kbase = kp  + (size_t)(b*4096 + split*1024)*128;
  const unsigned short* vbase = vpt + (size_t)b*128*4096 + split*1024;
  const float* bbase = biasc + b*4096 + split*1024;

  gload16(bbase + w*256 + lane*4, &Bs[w*256]);
  bf16x8 qf[8];
  {
    const unsigned short* qrow = qp + ((size_t)(b*4096 + q0 + wr*32 + l31))*128;
    #pragma unroll
    for (int kk=0;kk<8;kk++) qf[kk] = *(const bf16x8*)(qrow + kk*16 + hi*8);
  }

  // stage tile k0_ (32 keys) into buffer bf_: 2 K-gloads + 2 V-gloads /thread
  #define STAGE(bf_, k0_) do{                                                 \
    const char* kb_ = (const char*)kbase + (size_t)(k0_)*256;                 \
    _Pragma("unroll")                                                         \
    for (int i=0;i<2;i++){                                                    \
      int s_  = w*2+i;                                                        \
      int row = s_*4 + (lane>>4);                                             \
      int cb  = (lane&15)*16;                                                 \
      gload16(kb_ + row*256 + (cb ^ ((row&7)*16)),                            \
              (char*)Ks[bf_] + s_*1024);                                      \
    }                                                                         \
    const char* vb_ = (const char*)vbase + (size_t)(k0_)*2;                   \
    _Pragma("unroll")                                                         \
    for (int i=0;i<2;i++){                                                    \
      int s_  = w*2+i;                                                        \
      int rp  = s_*8 + (lane>>3);                                             \
      int qx  = ((lane&7)*16) ^ ((rp&7)*16);                                  \
      int d_  = rp*2 + (qx>>6);                                               \
      gload16(vb_ + (size_t)d_*8192 + (qx&63),                                \
              (char*)Vs[bf_] + s_*1024);                                      \
    }                                                                         \
  }while(0)

  float m_run = -INFINITY, l_run = 0.f;
  f32x16 acc0 = {}, acc1 = {};

  STAGE(0, 0);
  __syncthreads();   // drains bias + tile0 loads

  // V read offsets (constant per lane; rp1 = rp0+16 has same &7)
  const int vrp0  = wc*32 + (l31>>1);
  const int vbyt0 = (l31&1)*64;

  for (int t=0;t<32;t++){
    const int cur = t & 1;
    if (t<31) STAGE(cur^1, (t+1)*32);   // issue early; drained at tile-end barrier

    const unsigned short* Kc = Ks[cur];
    const char* Vc = (const char*)Vs[cur];

    // ---- QK^T (swapped): lane holds 16 P-values for q = wr*32+l31
    f32x16 sc = {};
    __builtin_amdgcn_s_setprio(1);
    #pragma unroll
    for (int kk=0;kk<8;kk++){
      bf16x8 a0 = *(const bf16x8*)&Kc[SWZ128(l31, kk*16 + hi*8)];
      sc = MFMA32(a0, qf[kk], sc);
    }
    __builtin_amdgcn_s_setprio(0);

    // ---- bias add + tile max (lane's k = c + 8*rg + 4*hi)
    const float* Bt = &Bs[t*32];
    float tmax = -1e30f;
    #pragma unroll
    for (int rg=0; rg<4; rg++){
      float4 b0 = *(const float4*)&Bt[rg*8 + hi*4];
      #pragma unroll
      for (int c=0;c<4;c++){
        sc[rg*4+c] += ((const float*)&b0)[c];
        tmax = fmaxf(tmax, sc[rg*4+c]);
      }
    }
    tmax = fmaxf(tmax, __shfl_xor(tmax, 32));

    // ---- defer-max (log2 units; exact when skipped: corr==1)
    if (!__all(tmax <= m_run + THR_L2)){
      float mn = fmaxf(m_run, tmax);
      float corr = __builtin_exp2f(m_run - mn);
      m_run = mn;
      l_run *= corr;
      #pragma unroll
      for (int reg=0; reg<16; reg++){
        int qn = (reg&3) + 8*(reg>>2) + 4*hi;
        float ca = __shfl(corr, qn);
        acc0[reg] *= ca; acc1[reg] *= ca;
      }
    }

    // ---- exp2 + row sum
    float rs = 0.f;
    #pragma unroll
    for (int i=0;i<16;i++){
      sc[i] = __builtin_exp2f(sc[i]-m_run); rs += sc[i];
    }
    rs += __shfl_xor(rs, 32);
    l_run += rs;

    // ---- pack P to bf16 (pk[rg*2+p] = k = 8rg+4hi+2p, +1)
    unsigned pk[8];
    #pragma unroll
    for (int rg=0; rg<4; rg++){
      pk[rg*2+0] = cvtpk(sc[rg*4+0], sc[rg*4+1]);
      pk[rg*2+1] = cvtpk(sc[rg*4+2], sc[rg*4+3]);
    }

    // ---- A-frag half-exchange + PV (kt over 2 k-halves of 16)
    __builtin_amdgcn_s_setprio(1);
    #pragma unroll
    for (int kt=0; kt<2; kt++){
      unsigned X0 = pk[kt*4+0], X1 = pk[kt*4+1];
      unsigned Y0 = pk[kt*4+2], Y1 = pk[kt*4+3];
      unsigned X0s = __shfl_xor(X0,32), X1s = __shfl_xor(X1,32);
      unsigned Y0s = __shfl_xor(Y0,32), Y1s = __shfl_xor(Y1,32);
      union { unsigned u[4]; bf16x8 v; } pu;
      pu.u[0] = hi ? Y0s : X0;
      pu.u[1] = hi ? Y1s : X1;
      pu.u[2] = hi ? Y0  : X0s;
      pu.u[3] = hi ? Y1  : X1s;
      int koff = kt*32 + hi*16;
      bf16x8 v0 = *(const bf16x8*)(Vc + vrp0*128      + ((vbyt0 + koff) ^ ((vrp0&7)*16)));
      bf16x8 v1 = *(const bf16x8*)(Vc + (vrp0+16)*128 + ((vbyt0 + koff) ^ ((vrp0&7)*16)));
      acc0 = MFMA32(pu.v, v0, acc0);
      acc1 = MFMA32(pu.v, v1, acc1);
    }
    __builtin_amdgcn_s_setprio(0);

    // one barrier/tile: drains STAGE(t+1) vmcnt and closes reads of buf cur.
    __syncthreads();
  }
  #undef STAGE

  // ---- epilogue
  const size_t rowbase = (size_t)split*16384 + (size_t)b*4096 + q0;
  #pragma unroll
  for (int reg=0; reg<16; reg++){
    int qn = (reg&3) + 8*(reg>>2) + 4*hi;
    float lv = __shfl(l_run, qn);
    float inv = 1.f/lv;
    size_t row = rowbase + wr*32 + qn;
    opart[row*128 + wc*64 +      l31] = f2bf(acc0[reg]*inv);
    opart[row*128 + wc*64 + 32 + l31] = f2bf(acc1[reg]*inv);
  }
  if (hi==0){
    size_t rg = rowbase + wr*32 + l31;
    ml[rg*2]   = m_run;     // log2 domain
    ml[rg*2+1] = l_run;
  }
}

// ---------------------------------------------------------------------------
// Kernel 3: merge 4 KV-split partials + out-projection. (m in log2 domain)
// ---------------------------------------------------------------------------
__global__ __launch_bounds__(256) void k_outproj(
    const unsigned short* __restrict__ opart, const float* __restrict__ ml,
    const float* __restrict__ p_w, const float* __restrict__ p_b,
    float* __restrict__ out)
{
  const int tid = threadIdx.x;
  const int row0 = blockIdx.x*64;
  __shared__ __align__(16) unsigned short Wt[128][136];
  __shared__ __align__(16) unsigned short Xs[64][136];
  __shared__ float wmg[4][64];

  #pragma unroll 4
  for (int i=0;i<16;i++){
    int idx = tid*64 + i*4;
    float4 v4 = *(const float4*)(p_w + idx);
    Wt[(idx+0)&127][(idx+0)>>7] = f2bf(v4.x);
    Wt[(idx+1)&127][(idx+1)>>7] = f2bf(v4.y);
    Wt[(idx+2)&127][(idx+2)>>7] = f2bf(v4.z);
    Wt[(idx+3)&127][(idx+3)>>7] = f2bf(v4.w);
  }
  if (tid < 64){
    int row = row0 + tid;
    float m[4], l[4];
    #pragma unroll
    for (int i=0;i<4;i++){
      m[i] = ml[((size_t)i*16384 + row)*2];
      l[i] = ml[((size_t)i*16384 + row)*2 + 1];
    }
    float M = fmaxf(fmaxf(m[0],m[1]),fmaxf(m[2],m[3]));
    float wi[4], wsum = 0.f;
    #pragma unroll
    for (int i=0;i<4;i++){ wi[i] = __builtin_exp2f(m[i]-M)*l[i]; wsum += wi[i]; }
    float inv = 1.f/wsum;
    #pragma unroll
    for (int i=0;i<4;i++) wmg[i][tid] = wi[i]*inv;
  }
  __syncthreads();
  #pragma unroll
  for (int i=0;i<4;i++){
    int e = tid*32 + i*8;
    int row = e>>7, col = e&127;
    float a8[8];
    #pragma unroll
    for (int j=0;j<8;j++) a8[j] = 0.f;
    #pragma unroll
    for (int s=0;s<4;s++){
      uint4 v = *(const uint4*)(opart + ((size_t)s*16384 + row0 + row)*128 + col);
      float wv = wmg[s][row];
      const unsigned short* hp = (const unsigned short*)&v;
      #pragma unroll
      for (int j=0;j<8;j++) a8[j] += wv * bf2f(hp[j]);
    }
    unsigned short h8[8];
    #pragma unroll
    for (int j=0;j<8;j++) h8[j] = f2bf(a8[j]);
    *(uint4*)&Xs[row][col] = *(const uint4*)h8;
  }
  __syncthreads();

  const int w=tid>>6, lane=tid&63, lr=lane&15, lg=lane>>4;
  f32x4 acc[8];
  #pragma unroll
  for (int nt=0;nt<8;nt++) acc[nt] = (f32x4){0.f,0.f,0.f,0.f};
  #pragma unroll
  for (int kk=0;kk<4;kk++){
    bf16x8 a = *(const bf16x8*)&Xs[w*16+lr][kk*32+lg*8];
    #pragma unroll
    for (int nt=0;nt<8;nt++){
      bf16x8 bb = *(const bf16x8*)&Wt[nt*16+lr][kk*32+lg*8];
      acc[nt] = MFMA16(a,bb,acc[nt]);
    }
  }
  #pragma unroll
  for (int nt=0;nt<8;nt++){
    int col = nt*16+lr;
    float pb = p_b[col];
    #pragma unroll
    for (int r=0;r<4;r++){
      int row = row0 + w*16 + lg*4 + r;
      out[(size_t)row*128+col] = acc[nt][r] + pb;
    }
  }
}

extern "C" void kernel_launch(void* const* d_in, const int* in_sizes, int n_in,
                              void* d_out, int out_size, void* d_ws, size_t ws_size,
                              hipStream_t stream) {
  (void)in_sizes; (void)n_in; (void)out_size; (void)ws_size;
  const float* query    = (const float*)d_in[0];
  const float* key      = (const float*)d_in[1];
  const float* value    = (const float*)d_in[2];
  const float* att_bias = (const float*)d_in[3];
  const float* q_w = (const float*)d_in[4];
  const float* q_b = (const float*)d_in[5];
  const float* k_w = (const float*)d_in[6];
  const float* v_w = (const float*)d_in[7];
  const float* v_b = (const float*)d_in[8];
  const float* vs_w = (const float*)d_in[9];
  const float* vs_b = (const float*)d_in[10];
  const float* p_w = (const float*)d_in[11];
  const float* p_b = (const float*)d_in[12];

  char* ws = (char*)d_ws;
  unsigned short* qp    = (unsigned short*)(ws);             // 4 MB
  unsigned short* kp    = (unsigned short*)(ws + 4194304);   // 4 MB
  unsigned short* vpt   = (unsigned short*)(ws + 8388608);   // 4 MB  [b][d][n]
  float*          biasc = (float*)(ws + 12582912);           // 64 KB
  unsigned short* opart = (unsigned short*)(ws + 12648448);  // 16 MB
  float*          ml    = (float*)(ws + 29425664);           // 512 KB

  hipLaunchKernelGGL(k_proj, dim3(256,3), dim3(256), 0, stream,
    query,key,value,att_bias,q_w,q_b,k_w,v_w,v_b,vs_w,vs_b,qp,kp,vpt,biasc);
  hipLaunchKernelGGL(k_flash, dim3(1024), dim3(256), 0, stream,
    qp,kp,vpt,biasc,opart,ml);
  hipLaunchKernelGGL(k_outproj, dim3(256), dim3(256), 0, stream,
    opart,ml,p_w,p_b,(float*)d_out);
}

// Round 7
// 88.199 us; speedup vs baseline: 2.1564x; 1.2889x over previous
//
#include <hip/hip_runtime.h>

typedef __bf16 bf16x8 __attribute__((ext_vector_type(8)));
typedef float f32x4 __attribute__((ext_vector_type(4)));

#define MFMA16(a,b,c) __builtin_amdgcn_mfma_f32_16x16x32_bf16(a,b,c,0,0,0)

static __device__ __forceinline__ unsigned short f2bf(float f){
  union{float f;unsigned u;}v; v.f=f;
  unsigned u=v.u;
  u += 0x7fffu + ((u>>16)&1u);
  return (unsigned short)(u>>16);
}
static __device__ __forceinline__ float bf2f(unsigned short h){
  union{unsigned u;float f;}v; v.u=((unsigned)h)<<16; return v.f;
}
static __device__ __forceinline__ unsigned cvtpk(float lo, float hi){
  unsigned r;
  asm("v_cvt_pk_bf16_f32 %0, %1, %2" : "=v"(r) : "v"(lo), "v"(hi));
  return r;
}
static __device__ __forceinline__ void gload16(const void* g, void* l){
  __builtin_amdgcn_global_load_lds(
    (const __attribute__((address_space(1))) unsigned int*)(uintptr_t)g,
    (__attribute__((address_space(3))) unsigned int*)(uintptr_t)l,
    16, 0, 0);
}

#define SCALE_QK 0.08838834764831845f
#define LOG2E    1.44269504088896340f
#define THR_L2   11.541560327111708f   /* 8 nat-units * log2e */

// 16B-granule XOR swizzle for 256B-stride K tiles (short index)
#define SWZ128(r,c) (((r)<<7) + ((c) ^ (((r)&7)<<3)))

// PV k-map permutation: P's S^T layout gives lane(g) slots j=0..7 the keys
// h(g,j) = 4g + (j&3) + 16*(j>>2). V is stored with keys permuted within each
// 32-group so that slot order is CONTIGUOUS: pos(k) = 8*((k>>2)&3)+(k&3)+4*(k>>4).
// Then PV's A-frag = cvtpk(sc) in order (no lane exchange) and B-frag = b128.

// ---------------------------------------------------------------------------
// Kernel 1: q/k/v projections (bf16) + combined per-key bias (log2 domain).
//   t=0: qp = (query@q_w + q_b)*SCALE*LOG2E   t=1: kp = key@k_w
//   t=2: vpt[b][d][pos-permuted n] = (value@v_w + v_b)^T ; biasc (log2)
// ---------------------------------------------------------------------------
__global__ __launch_bounds__(256) void k_proj(
    const float* __restrict__ query, const float* __restrict__ key,
    const float* __restrict__ value, const float* __restrict__ att_bias,
    const float* __restrict__ q_w, const float* __restrict__ q_b,
    const float* __restrict__ k_w, const float* __restrict__ v_w,
    const float* __restrict__ v_b, const float* __restrict__ vs_w,
    const float* __restrict__ vs_b,
    unsigned short* __restrict__ qp, unsigned short* __restrict__ kp,
    unsigned short* __restrict__ vpt, float* __restrict__ biasc)
{
  const int t = blockIdx.y;
  const float* X = (t==0) ? query : ((t==1) ? key : value);
  const float* W = (t==0) ? q_w  : ((t==1) ? k_w : v_w);
  const int tid = threadIdx.x;
  const int row0 = blockIdx.x * 64;

  __shared__ __align__(16) unsigned short Wt[128][136];
  __shared__ __align__(16) unsigned short Xs[64][136];
  __shared__ float vsw_s[128];

  #pragma unroll 4
  for (int i=0;i<16;i++){
    int idx = tid*64 + i*4;
    float4 v4 = *(const float4*)(W + idx);
    Wt[(idx+0)&127][(idx+0)>>7] = f2bf(v4.x);
    Wt[(idx+1)&127][(idx+1)>>7] = f2bf(v4.y);
    Wt[(idx+2)&127][(idx+2)>>7] = f2bf(v4.z);
    Wt[(idx+3)&127][(idx+3)>>7] = f2bf(v4.w);
  }
  {
    const float* Xb = X + (size_t)row0*128;
    #pragma unroll
    for (int i=0;i<8;i++){
      int f4 = i*256 + tid;
      int row = f4>>5, c4 = f4&31;
      float4 v = *(const float4*)(Xb + row*128 + c4*4);
      ushort4 h;
      h.x = f2bf(v.x); h.y = f2bf(v.y); h.z = f2bf(v.z); h.w = f2bf(v.w);
      *(ushort4*)&Xs[row][c4*4] = h;
    }
  }
  if (t==2 && tid<128) vsw_s[tid] = vs_w[tid];
  __syncthreads();

  const int w = tid>>6, lane = tid&63, lr = lane&15, lg = lane>>4;
  f32x4 acc[8];
  #pragma unroll
  for (int nt=0;nt<8;nt++) acc[nt] = (f32x4){0.f,0.f,0.f,0.f};
  #pragma unroll
  for (int kk=0;kk<4;kk++){
    bf16x8 a = *(const bf16x8*)&Xs[w*16+lr][kk*32+lg*8];
    #pragma unroll
    for (int nt=0;nt<8;nt++){
      bf16x8 bb = *(const bf16x8*)&Wt[nt*16+lr][kk*32+lg*8];
      acc[nt] = MFMA16(a,bb,acc[nt]);
    }
  }
  const float* bias = (t==0) ? q_b : ((t==2) ? v_b : (const float*)nullptr);
  const float sc = (t==0) ? (SCALE_QK*LOG2E) : 1.f;
  #pragma unroll
  for (int nt=0;nt<8;nt++){
    int col = nt*16+lr;
    float bv = bias ? bias[col] : 0.f;
    #pragma unroll
    for (int r=0;r<4;r++){
      int row = row0 + w*16 + lg*4 + r;
      unsigned short h = f2bf((acc[nt][r] + bv) * sc);
      if (t==0)      qp[(size_t)row*128+col] = h;
      else if (t==1) kp[(size_t)row*128+col] = h;
      else {
        int bi = row>>12, n = row&4095;
        int k5 = n & 31;
        int pos = 8*((k5>>2)&3) + (k5&3) + 4*(k5>>4);  // PV k-map permutation
        int np = (n & ~31) | pos;
        vpt[((size_t)bi*128+col)*4096 + np] = h;
      }
    }
  }
  if (t==2){
    int rl = tid>>2, part = tid&3;
    float s = 0.f;
    #pragma unroll
    for (int j=0;j<32;j++){
      int d = part*32+j;
      s += bf2f(Xs[rl][d]) * vsw_s[d];
    }
    s += __shfl_xor(s,1);
    s += __shfl_xor(s,2);
    if ((tid&3)==0){
      int rg = row0 + rl;
      biasc[rg] = (s + vs_b[0] + att_bias[rg]) * LOG2E;
    }
  }
}

// ---------------------------------------------------------------------------
// Kernel 2: flash attention. q-split waves (16 q x full d=128 each), 16x16x32
//   MFMA, swapped QK^T, in-lane exp2 softmax (8 exps/lane, NO duplication),
//   defer-max. PV A-frag = cvtpk(sc) in-order (permuted-V k-map), B = b128.
//   KVBLK=32 double-buffered, one barrier/tile, STAGE-before-compute.
//   LDS = 2*8K(K) + 2*8K(V) + 4K(bias) = 36KB -> 4 blocks/CU.
// ---------------------------------------------------------------------------
__global__ __launch_bounds__(256,4) void k_flash(
    const unsigned short* __restrict__ qp, const unsigned short* __restrict__ kp,
    const unsigned short* __restrict__ vpt, const float* __restrict__ biasc,
    unsigned short* __restrict__ opart, float* __restrict__ ml)
{
  // XCD-aware decode (bijective over 1024 blocks; xcd = blk&7)
  const int f = blockIdx.x;
  const int xcd = f & 7, slot = f >> 3;
  const int group = xcd*2 + (slot>>6);
  const int b = group>>2, split = group&3;
  const int q0 = (slot & 63) * 64;

  const int tid = threadIdx.x;
  const int w = tid>>6, lane = tid&63;
  const int q15 = lane&15, g = lane>>4;

  __shared__ __align__(16) unsigned short Ks[2][32*128];  // [k][d] swizzled
  __shared__ __align__(16) unsigned short Vs[2][128*32];  // [d][pos] swizzled
  __shared__ __align__(16) float Bs[1024];

  const unsigned short* kbase = kp  + (size_t)(b*4096 + split*1024)*128;
  const unsigned short* vbase = vpt + (size_t)b*128*4096 + split*1024;
  const float* bbase = biasc + b*4096 + split*1024;

  gload16(bbase + w*256 + lane*4, &Bs[w*256]);
  bf16x8 qf[4];
  {
    const unsigned short* qrow = qp + ((size_t)(b*4096 + q0 + w*16 + q15))*128;
    #pragma unroll
    for (int kk=0;kk<4;kk++) qf[kk] = *(const bf16x8*)(qrow + kk*32 + g*8);
  }

  // stage 32-key tile: K 8KB (4 rows/slot of 256B), V 8KB (16 rows/slot of 64B)
  #define STAGE(bf_, k0_) do{                                                 \
    const char* kb_ = (const char*)kbase + (size_t)(k0_)*256;                 \
    const char* vb_ = (const char*)vbase + (size_t)(k0_)*2;                   \
    _Pragma("unroll")                                                         \
    for (int i=0;i<2;i++){                                                    \
      int s_ = w*2+i;                                                         \
      int kr = s_*4 + (lane>>4);                                              \
      gload16(kb_ + kr*256 + (((lane&15)*16) ^ ((kr&7)*16)),                  \
              (char*)Ks[bf_] + s_*1024);                                      \
      int vd = s_*16 + (lane>>2);                                             \
      gload16(vb_ + (size_t)vd*8192 + (((lane&3) ^ (vd&3))*16),               \
              (char*)Vs[bf_] + s_*1024);                                      \
    }                                                                         \
  }while(0)

  float m_run = -INFINITY, l_run = 0.f;
  f32x4 acc[8];
  #pragma unroll
  for (int nt=0;nt<8;nt++) acc[nt] = (f32x4){0.f,0.f,0.f,0.f};

  STAGE(0, 0);
  __syncthreads();   // drains bias + tile0 loads

  // loop-invariant V read offset: granule = g ^ (d&3), d = nt*16+q15
  const int voff = (q15<<6) + ((g ^ (q15&3))<<4);

  for (int t=0;t<32;t++){
    const int cur = t & 1;
    if (t<31) STAGE(cur^1, (t+1)*32);

    const unsigned short* Kc = Ks[cur];
    const char* Vc = (const char*)Vs[cur];

    // ---- QK^T (swapped, 2 k-subtiles): lane holds S^T[k=4g+reg(+16)][q=q15]
    f32x4 s0 = {}, s1 = {};
    __builtin_amdgcn_s_setprio(1);
    #pragma unroll
    for (int kk=0;kk<4;kk++){
      bf16x8 a0 = *(const bf16x8*)&Kc[SWZ128(q15,      kk*32 + g*8)];
      bf16x8 a1 = *(const bf16x8*)&Kc[SWZ128(16 + q15, kk*32 + g*8)];
      s0 = MFMA16(a0, qf[kk], s0);
      s1 = MFMA16(a1, qf[kk], s1);
    }
    __builtin_amdgcn_s_setprio(0);

    // ---- bias add + tile max (lane's k = 4g+c (+16))
    const float* Bt = &Bs[t*32];
    float4 b0 = *(const float4*)&Bt[g*4];
    float4 b1 = *(const float4*)&Bt[16 + g*4];
    float tmax = -1e30f;
    #pragma unroll
    for (int c=0;c<4;c++){
      s0[c] += ((const float*)&b0)[c];
      s1[c] += ((const float*)&b1)[c];
      tmax = fmaxf(tmax, fmaxf(s0[c], s1[c]));
    }
    tmax = fmaxf(tmax, __shfl_xor(tmax, 16));
    tmax = fmaxf(tmax, __shfl_xor(tmax, 32));

    // ---- defer-max (log2 units; exact when skipped)
    if (!__all(tmax <= m_run + THR_L2)){
      float mn = fmaxf(m_run, tmax);
      float corr = __builtin_exp2f(m_run - mn);
      m_run = mn;
      l_run *= corr;
      float c0 = __shfl(corr, g*4+0);
      float c1 = __shfl(corr, g*4+1);
      float c2 = __shfl(corr, g*4+2);
      float c3 = __shfl(corr, g*4+3);
      #pragma unroll
      for (int nt=0;nt<8;nt++){
        acc[nt][0]*=c0; acc[nt][1]*=c1; acc[nt][2]*=c2; acc[nt][3]*=c3;
      }
    }

    // ---- exp2 + row sum (8 exps/lane)
    float rs = 0.f;
    #pragma unroll
    for (int c=0;c<4;c++){
      s0[c] = __builtin_exp2f(s0[c]-m_run); rs += s0[c];
      s1[c] = __builtin_exp2f(s1[c]-m_run); rs += s1[c];
    }
    rs += __shfl_xor(rs, 16);
    rs += __shfl_xor(rs, 32);
    l_run += rs;

    // ---- A-frag: slots j=0..7 = {s0[0..3], s1[0..3]} (h-map, no exchange)
    union { unsigned u[4]; bf16x8 v; } pu;
    pu.u[0] = cvtpk(s0[0], s0[1]);
    pu.u[1] = cvtpk(s0[2], s0[3]);
    pu.u[2] = cvtpk(s1[0], s1[1]);
    pu.u[3] = cvtpk(s1[2], s1[3]);

    // ---- PV: 8 d-tiles, B-frag contiguous b128 (permuted V)
    __builtin_amdgcn_s_setprio(1);
    #pragma unroll
    for (int nt=0;nt<8;nt++){
      bf16x8 vf = *(const bf16x8*)(Vc + voff + nt*1024);
      acc[nt] = MFMA16(pu.v, vf, acc[nt]);
    }
    __builtin_amdgcn_s_setprio(0);

    __syncthreads();   // drains STAGE(t+1), closes reads of buf cur
  }
  #undef STAGE

  // ---- epilogue: lane holds O[q=4g+reg][d=16nt+q15]
  const size_t rowbase = (size_t)split*16384 + (size_t)b*4096 + q0;
  float i0 = 1.f/__shfl(l_run, g*4+0);
  float i1 = 1.f/__shfl(l_run, g*4+1);
  float i2 = 1.f/__shfl(l_run, g*4+2);
  float i3 = 1.f/__shfl(l_run, g*4+3);
  #pragma unroll
  for (int nt=0;nt<8;nt++){
    int col = nt*16 + q15;
    size_t rb = rowbase + w*16 + g*4;
    opart[(rb+0)*128 + col] = f2bf(acc[nt][0]*i0);
    opart[(rb+1)*128 + col] = f2bf(acc[nt][1]*i1);
    opart[(rb+2)*128 + col] = f2bf(acc[nt][2]*i2);
    opart[(rb+3)*128 + col] = f2bf(acc[nt][3]*i3);
  }
  if (lane < 16){
    size_t rg = rowbase + w*16 + lane;
    ml[rg*2]   = m_run;     // log2 domain
    ml[rg*2+1] = l_run;
  }
}

// ---------------------------------------------------------------------------
// Kernel 3: merge 4 KV-split partials + out-projection. (m in log2 domain)
// ---------------------------------------------------------------------------
__global__ __launch_bounds__(256) void k_outproj(
    const unsigned short* __restrict__ opart, const float* __restrict__ ml,
    const float* __restrict__ p_w, const float* __restrict__ p_b,
    float* __restrict__ out)
{
  const int tid = threadIdx.x;
  const int row0 = blockIdx.x*64;
  __shared__ __align__(16) unsigned short Wt[128][136];
  __shared__ __align__(16) unsigned short Xs[64][136];
  __shared__ float wmg[4][64];

  #pragma unroll 4
  for (int i=0;i<16;i++){
    int idx = tid*64 + i*4;
    float4 v4 = *(const float4*)(p_w + idx);
    Wt[(idx+0)&127][(idx+0)>>7] = f2bf(v4.x);
    Wt[(idx+1)&127][(idx+1)>>7] = f2bf(v4.y);
    Wt[(idx+2)&127][(idx+2)>>7] = f2bf(v4.z);
    Wt[(idx+3)&127][(idx+3)>>7] = f2bf(v4.w);
  }
  if (tid < 64){
    int row = row0 + tid;
    float m[4], l[4];
    #pragma unroll
    for (int i=0;i<4;i++){
      m[i] = ml[((size_t)i*16384 + row)*2];
      l[i] = ml[((size_t)i*16384 + row)*2 + 1];
    }
    float M = fmaxf(fmaxf(m[0],m[1]),fmaxf(m[2],m[3]));
    float wi[4], wsum = 0.f;
    #pragma unroll
    for (int i=0;i<4;i++){ wi[i] = __builtin_exp2f(m[i]-M)*l[i]; wsum += wi[i]; }
    float inv = 1.f/wsum;
    #pragma unroll
    for (int i=0;i<4;i++) wmg[i][tid] = wi[i]*inv;
  }
  __syncthreads();
  #pragma unroll
  for (int i=0;i<4;i++){
    int e = tid*32 + i*8;
    int row = e>>7, col = e&127;
    float a8[8];
    #pragma unroll
    for (int j=0;j<8;j++) a8[j] = 0.f;
    #pragma unroll
    for (int s=0;s<4;s++){
      uint4 v = *(const uint4*)(opart + ((size_t)s*16384 + row0 + row)*128 + col);
      float wv = wmg[s][row];
      const unsigned short* hp = (const unsigned short*)&v;
      #pragma unroll
      for (int j=0;j<8;j++) a8[j] += wv * bf2f(hp[j]);
    }
    unsigned short h8[8];
    #pragma unroll
    for (int j=0;j<8;j++) h8[j] = f2bf(a8[j]);
    *(uint4*)&Xs[row][col] = *(const uint4*)h8;
  }
  __syncthreads();

  const int w=tid>>6, lane=tid&63, lr=lane&15, lg=lane>>4;
  f32x4 acc[8];
  #pragma unroll
  for (int nt=0;nt<8;nt++) acc[nt] = (f32x4){0.f,0.f,0.f,0.f};
  #pragma unroll
  for (int kk=0;kk<4;kk++){
    bf16x8 a = *(const bf16x8*)&Xs[w*16+lr][kk*32+lg*8];
    #pragma unroll
    for (int nt=0;nt<8;nt++){
      bf16x8 bb = *(const bf16x8*)&Wt[nt*16+lr][kk*32+lg*8];
      acc[nt] = MFMA16(a,bb,acc[nt]);
    }
  }
  #pragma unroll
  for (int nt=0;nt<8;nt++){
    int col = nt*16+lr;
    float pb = p_b[col];
    #pragma unroll
    for (int r=0;r<4;r++){
      int row = row0 + w*16 + lg*4 + r;
      out[(size_t)row*128+col] = acc[nt][r] + pb;
    }
  }
}

extern "C" void kernel_launch(void* const* d_in, const int* in_sizes, int n_in,
                              void* d_out, int out_size, void* d_ws, size_t ws_size,
                              hipStream_t stream) {
  (void)in_sizes; (void)n_in; (void)out_size; (void)ws_size;
  const float* query    = (const float*)d_in[0];
  const float* key      = (const float*)d_in[1];
  const float* value    = (const float*)d_in[2];
  const float* att_bias = (const float*)d_in[3];
  const float* q_w = (const float*)d_in[4];
  const float* q_b = (const float*)d_in[5];
  const float* k_w = (const float*)d_in[6];
  const float* v_w = (const float*)d_in[7];
  const float* v_b = (const float*)d_in[8];
  const float* vs_w = (const float*)d_in[9];
  const float* vs_b = (const float*)d_in[10];
  const float* p_w = (const float*)d_in[11];
  const float* p_b = (const float*)d_in[12];

  char* ws = (char*)d_ws;
  unsigned short* qp    = (unsigned short*)(ws);             // 4 MB
  unsigned short* kp    = (unsigned short*)(ws + 4194304);   // 4 MB
  unsigned short* vpt   = (unsigned short*)(ws + 8388608);   // 4 MB  [b][d][n-perm]
  float*          biasc = (float*)(ws + 12582912);           // 64 KB
  unsigned short* opart = (unsigned short*)(ws + 12648448);  // 16 MB
  float*          ml    = (float*)(ws + 29425664);           // 512 KB

  hipLaunchKernelGGL(k_proj, dim3(256,3), dim3(256), 0, stream,
    query,key,value,att_bias,q_w,q_b,k_w,v_w,v_b,vs_w,vs_b,qp,kp,vpt,biasc);
  hipLaunchKernelGGL(k_flash, dim3(1024), dim3(256), 0, stream,
    qp,kp,vpt,biasc,opart,ml);
  hipLaunchKernelGGL(k_outproj, dim3(256), dim3(256), 0, stream,
    opart,ml,p_w,p_b,(float*)d_out);
}